// Round 3
// baseline (1880.201 us; speedup 1.0000x reference)
//
#include <hip/hip_runtime.h>

#define N_IN    128
#define N_HID   15
#define N_HIDP  16
#define N_OUT   32

#define BSH     9            // bucket = node >> 9 (512 nodes/bucket)
#define BNODES  512
#define CAP     20480        // slots per bucket region (mean 16384, +32 sigma)
#define SLICES  2

// ---------------------------------------------------------------------------
// Detect int64 vs int32 edge payload: if int64, every odd 32-bit word (high
// word of a value < 2^31) is 0.
// ---------------------------------------------------------------------------
__global__ void detect_kernel(const int* __restrict__ idx, int* __restrict__ flag) {
    __shared__ int nz;
    if (threadIdx.x == 0) nz = 0;
    __syncthreads();
    if (idx[2 * threadIdx.x + 1] != 0) atomicOr(&nz, 1);
    __syncthreads();
    if (threadIdx.x == 0) *flag = (nz == 0) ? 1 : 0;
}

// ---------------------------------------------------------------------------
// Partition: edges -> per-bucket regions of packed (src<<9 | dst&511).
// Also computes deg[] (in-degree, no self-loops).
// Block = 512 threads, 16384 edges. Per-block run per bucket reserved with one
// global atomic, so each block advances only ~NB open write cursors -> the
// write frontier stays L2-resident and stores combine into full lines.
// ---------------------------------------------------------------------------
__global__ __launch_bounds__(512) void partition_kernel(
    const void* __restrict__ idx, int E, int NBk,
    const int* __restrict__ flag,
    unsigned* __restrict__ deg, int* __restrict__ gcnt,
    unsigned* __restrict__ payload) {
    __shared__ int hist[512];
    __shared__ int runbase[512];
    __shared__ int lcur[512];
    const int tid = threadIdx.x;
    const bool is64 = (*flag != 0);
    const long long base = (long long)blockIdx.x * 16384;
    const long long* p64 = (const long long*)idx;
    const int*       p32 = (const int*)idx;

    hist[tid] = 0;
    lcur[tid] = 0;
    __syncthreads();

    // phase 1: bucket histogram + degree count
    for (int k = 0; k < 32; ++k) {
        long long e = base + (long long)k * 512 + tid;
        if (e < E) {
            int d = is64 ? (int)p64[E + e] : p32[E + e];
            atomicAdd(&deg[d], 1u);
            atomicAdd(&hist[d >> BSH], 1);
        }
    }
    __syncthreads();

    // phase 2: reserve this block's run inside each bucket region
    int myCnt = (tid < NBk) ? hist[tid] : 0;
    int myBase = 0;
    if (myCnt > 0) myBase = atomicAdd(&gcnt[tid], myCnt);
    runbase[tid] = myBase;
    __syncthreads();

    // phase 3: scatter packed edges
    for (int k = 0; k < 32; ++k) {
        long long e = base + (long long)k * 512 + tid;
        if (e < E) {
            int s = is64 ? (int)p64[e] : p32[e];
            int d = is64 ? (int)p64[E + e] : p32[E + e];
            int b = d >> BSH;
            int pos = atomicAdd(&lcur[b], 1);
            payload[(size_t)b * CAP + runbase[b] + pos] =
                ((unsigned)s << BSH) | (unsigned)(d & (BNODES - 1));
        }
    }
}

__global__ void dinv_kernel(const unsigned* __restrict__ deg,
                            float* __restrict__ dinv, int N) {
    int i = blockIdx.x * 256 + threadIdx.x;
    if (i < N) dinv[i] = rsqrtf((float)deg[i] + 1.0f);  // +1 = self-loop
}

// ---------------------------------------------------------------------------
// GEMM1: hs[i][c] = (x[i] @ W1[:,c]) * dinv[i], padded to 16 ch (ch15 = 0).
// ---------------------------------------------------------------------------
__global__ __launch_bounds__(256) void gemm1_kernel(
    const float* __restrict__ x, const float* __restrict__ W1,
    const float* __restrict__ dinv, float* __restrict__ hs, int N) {
    __shared__ float Wl[N_IN * N_HIDP];
    for (int i = threadIdx.x; i < N_IN * N_HIDP; i += 256) {
        int k = i >> 4, c = i & 15;
        Wl[i] = (c < N_HID) ? W1[k * N_HID + c] : 0.f;
    }
    __syncthreads();
    const float4* __restrict__ Wl4 = (const float4*)Wl;
    const float4* __restrict__ x4  = (const float4*)x;

    int r0 = blockIdx.x * 512 + threadIdx.x;
    int r1 = r0 + 256;
    int r0c = r0 < N ? r0 : N - 1;
    int r1c = r1 < N ? r1 : N - 1;

    float acc0[16], acc1[16];
#pragma unroll
    for (int c = 0; c < 16; ++c) { acc0[c] = 0.f; acc1[c] = 0.f; }

    for (int k4 = 0; k4 < 32; ++k4) {
        float4 xv0 = x4[r0c * 32 + k4];
        float4 xv1 = x4[r1c * 32 + k4];
        float xs0[4] = {xv0.x, xv0.y, xv0.z, xv0.w};
        float xs1[4] = {xv1.x, xv1.y, xv1.z, xv1.w};
#pragma unroll
        for (int t = 0; t < 4; ++t) {
            int k = k4 * 4 + t;
            float4 wa = Wl4[k * 4 + 0];
            float4 wb = Wl4[k * 4 + 1];
            float4 wc = Wl4[k * 4 + 2];
            float4 wd = Wl4[k * 4 + 3];
            float wf[16] = {wa.x, wa.y, wa.z, wa.w, wb.x, wb.y, wb.z, wb.w,
                            wc.x, wc.y, wc.z, wc.w, wd.x, wd.y, wd.z, wd.w};
#pragma unroll
            for (int c = 0; c < 16; ++c) {
                acc0[c] = fmaf(xs0[t], wf[c], acc0[c]);
                acc1[c] = fmaf(xs1[t], wf[c], acc1[c]);
            }
        }
    }
    float4* __restrict__ hs4 = (float4*)hs;
    if (r0 < N) {
        float di = dinv[r0];
#pragma unroll
        for (int j = 0; j < 4; ++j)
            hs4[r0 * 4 + j] = make_float4(acc0[4*j]*di, acc0[4*j+1]*di,
                                          acc0[4*j+2]*di, acc0[4*j+3]*di);
    }
    if (r1 < N) {
        float di = dinv[r1];
#pragma unroll
        for (int j = 0; j < 4; ++j)
            hs4[r1 * 4 + j] = make_float4(acc1[4*j]*di, acc1[4*j+1]*di,
                                          acc1[4*j+2]*di, acc1[4*j+3]*di);
    }
}

// ---------------------------------------------------------------------------
// Agg: one block per (bucket, slice). Accumulate messages into a 512x16 LDS
// table (stride 17 vs bank conflicts) with ds_add_f32, then dump the partial
// table coalesced to part[blockIdx]. No global float atomics anywhere.
// ---------------------------------------------------------------------------
__global__ __launch_bounds__(256) void agg_kernel(
    const unsigned* __restrict__ payload, const int* __restrict__ gcnt,
    const float* __restrict__ feat, float* __restrict__ part) {
    __shared__ float acc[BNODES * 17];
    const int tid = threadIdx.x;
    const int bucket = blockIdx.x >> 1;
    const int slice  = blockIdx.x & 1;

    for (int k = tid; k < BNODES * 17; k += 256) acc[k] = 0.f;
    __syncthreads();

    int cnt = gcnt[bucket];
    if (cnt > CAP) cnt = CAP;
    int half = (cnt + 1) >> 1;
    int s0 = slice * half;
    int s1 = min(cnt, s0 + half);

    const unsigned* __restrict__ pay = payload + (size_t)bucket * CAP;
    const int c  = tid & 15;
    const int el = tid >> 4;  // 0..15

    int j = s0 + el;
    // 2x unrolled to keep two gathers in flight per lane
    for (; j + 16 < s1; j += 32) {
        unsigned pk0 = pay[j];
        unsigned pk1 = pay[j + 16];
        float v0 = feat[(size_t)(pk0 >> BSH) * N_HIDP + c];
        float v1 = feat[(size_t)(pk1 >> BSH) * N_HIDP + c];
        atomicAdd(&acc[(pk0 & (BNODES - 1)) * 17 + c], v0);
        atomicAdd(&acc[(pk1 & (BNODES - 1)) * 17 + c], v1);
    }
    if (j < s1) {
        unsigned pk = pay[j];
        float v = feat[(size_t)(pk >> BSH) * N_HIDP + c];
        atomicAdd(&acc[(pk & (BNODES - 1)) * 17 + c], v);
    }
    __syncthreads();

    float* __restrict__ outp = part + (size_t)blockIdx.x * (BNODES * N_HIDP);
    for (int k = tid; k < BNODES * N_HIDP; k += 256)
        outp[k] = acc[(k >> 4) * 17 + (k & 15)];
}

// finalize1: hs2[i][c] = relu(dinv*(part0+part1+hs_self) + b1) * dinv
__global__ void finalize1_kernel(const float* __restrict__ part,
                                 const float* __restrict__ hs,
                                 const float* __restrict__ dinv,
                                 const float* __restrict__ b1,
                                 float* __restrict__ hs2, int N) {
    int t = blockIdx.x * 256 + threadIdx.x;
    int i = t >> 4, c = t & 15;
    if (i >= N) return;
    int bucket = i >> BSH, n = i & (BNODES - 1);
    size_t o0 = ((size_t)(bucket * 2)) * (BNODES * N_HIDP) + n * N_HIDP + c;
    size_t o1 = o0 + (size_t)(BNODES * N_HIDP);
    float di = dinv[i];
    float sum = part[o0] + part[o1] + hs[(size_t)i * N_HIDP + c];
    float b = (c < N_HID) ? b1[c] : 0.f;
    float v = fmaxf(di * sum + b, 0.f);
    hs2[(size_t)i * N_HIDP + c] = v * di;
}

// finalize2: out[i] = (dinv*(part0+part1+hs2_self)) @ W2 + b2, LDS-staged u.
__global__ __launch_bounds__(256) void finalize2_kernel(
    const float* __restrict__ part, const float* __restrict__ hs2,
    const float* __restrict__ dinv, const float* __restrict__ W2,
    const float* __restrict__ b2, float* __restrict__ out, int N) {
    __shared__ float W2l[N_HIDP * N_OUT];
    __shared__ float ubuf[16][17];
    for (int t = threadIdx.x; t < N_HIDP * N_OUT; t += 256)
        W2l[t] = (t < N_HID * N_OUT) ? W2[t] : 0.f;

    int c = threadIdx.x & 15, q = threadIdx.x >> 4;
    int i = blockIdx.x * 16 + q;
    int iw = i < N ? i : N - 1;
    int bucket = iw >> BSH, n = iw & (BNODES - 1);
    size_t o0 = ((size_t)(bucket * 2)) * (BNODES * N_HIDP) + n * N_HIDP + c;
    size_t o1 = o0 + (size_t)(BNODES * N_HIDP);
    float di = dinv[iw];
    ubuf[q][c] = di * (part[o0] + part[o1] + hs2[(size_t)iw * N_HIDP + c]);
    __syncthreads();

    float a0 = b2[c], a1 = b2[c + 16];
#pragma unroll
    for (int k = 0; k < N_HID; ++k) {
        float uv = ubuf[q][k];
        a0 = fmaf(uv, W2l[k * N_OUT + c], a0);
        a1 = fmaf(uv, W2l[k * N_OUT + c + 16], a1);
    }
    if (i < N) {
        out[(size_t)i * N_OUT + c] = a0;
        out[(size_t)i * N_OUT + c + 16] = a1;
    }
}

// ---------------------------------------------------------------------------
extern "C" void kernel_launch(void* const* d_in, const int* in_sizes, int n_in,
                              void* d_out, int out_size, void* d_ws, size_t ws_size,
                              hipStream_t stream) {
    const float* x   = (const float*)d_in[0];
    const void*  eix = d_in[1];
    const float* W1  = (const float*)d_in[2];
    const float* b1  = (const float*)d_in[3];
    const float* W2  = (const float*)d_in[4];
    const float* b2  = (const float*)d_in[5];
    float* out = (float*)d_out;

    const int N = in_sizes[0] / N_IN;   // 200000
    const int E = in_sizes[1] / 2;      // 6400000
    const int NB = (N + BNODES - 1) >> BSH;  // 391

    char* ws = (char*)d_ws;
    size_t off = 0;
    auto alloc = [&](size_t bytes) -> void* {
        void* p = ws + off;
        off += (bytes + 255) & ~(size_t)255;
        return p;
    };
    unsigned* payload = (unsigned*)alloc((size_t)NB * CAP * 4);          // 32.0 MB
    float*    part    = (float*)alloc((size_t)NB * SLICES * BNODES * N_HIDP * 4); // 25.6 MB
    unsigned* deg     = (unsigned*)alloc((size_t)N * 4);
    float*    dinv    = (float*)alloc((size_t)N * 4);
    float*    hs      = (float*)alloc((size_t)N * N_HIDP * 4);
    float*    hs2     = (float*)alloc((size_t)N * N_HIDP * 4);
    int*      gcnt    = (int*)alloc((size_t)NB * 4);
    int*      flag    = (int*)alloc(256);

    hipMemsetAsync(deg, 0, (size_t)N * 4, stream);
    hipMemsetAsync(gcnt, 0, (size_t)NB * 4, stream);

    detect_kernel<<<1, 256, 0, stream>>>((const int*)eix, flag);

    const int npart = (E + 16383) / 16384;  // 391
    partition_kernel<<<npart, 512, 0, stream>>>(eix, E, NB, flag, deg, gcnt, payload);

    dinv_kernel<<<(N + 255) / 256, 256, 0, stream>>>(deg, dinv, N);
    gemm1_kernel<<<(N + 511) / 512, 256, 0, stream>>>(x, W1, dinv, hs, N);

    const int nagg = NB * SLICES;  // 782
    agg_kernel<<<nagg, 256, 0, stream>>>(payload, gcnt, hs, part);
    finalize1_kernel<<<(N * 16 + 255) / 256, 256, 0, stream>>>(part, hs, dinv, b1, hs2, N);

    agg_kernel<<<nagg, 256, 0, stream>>>(payload, gcnt, hs2, part);
    finalize2_kernel<<<(N + 15) / 16, 256, 0, stream>>>(part, hs2, dinv, W2, b2, out, N);
}

// Round 4
// 1670.649 us; speedup vs baseline: 1.1254x; 1.1254x over previous
//
#include <hip/hip_runtime.h>

#define N_IN    128
#define N_HID   15
#define N_HIDP  16
#define N_OUT   32

#define BSH     8            // bucket = node >> 8 (256 nodes/bucket)
#define BNODES  256
#define CAP     10240        // slots per bucket region (mean 8184, +23 sigma)
#define SLICES  4

// ---------------------------------------------------------------------------
// Detect int64 vs int32 edge payload: if int64, every odd 32-bit word (high
// word of a value < 2^31) is 0.
// ---------------------------------------------------------------------------
__global__ void detect_kernel(const int* __restrict__ idx, int* __restrict__ flag) {
    __shared__ int nz;
    if (threadIdx.x == 0) nz = 0;
    __syncthreads();
    if (idx[2 * threadIdx.x + 1] != 0) atomicOr(&nz, 1);
    __syncthreads();
    if (threadIdx.x == 0) *flag = (nz == 0) ? 1 : 0;
}

// ---------------------------------------------------------------------------
// Partition: edges -> per-bucket regions of packed (src<<8 | dst&255).
// Also computes deg[] (in-degree, no self-loops). Per-block run per bucket
// reserved with one global atomic -> write frontier stays L2-resident.
// ---------------------------------------------------------------------------
__global__ __launch_bounds__(512) void partition_kernel(
    const void* __restrict__ idx, int E, int NBk,
    const int* __restrict__ flag,
    unsigned* __restrict__ deg, int* __restrict__ gcnt,
    unsigned* __restrict__ payload) {
    __shared__ int hist[800];
    __shared__ int runbase[800];
    __shared__ int lcur[800];
    const int tid = threadIdx.x;
    const bool is64 = (*flag != 0);
    const long long base = (long long)blockIdx.x * 16384;
    const long long* p64 = (const long long*)idx;
    const int*       p32 = (const int*)idx;

    for (int t = tid; t < NBk; t += 512) { hist[t] = 0; lcur[t] = 0; }
    __syncthreads();

    // phase 1: bucket histogram + degree count
    for (int k = 0; k < 32; ++k) {
        long long e = base + (long long)k * 512 + tid;
        if (e < E) {
            int d = is64 ? (int)p64[E + e] : p32[E + e];
            atomicAdd(&deg[d], 1u);
            atomicAdd(&hist[d >> BSH], 1);
        }
    }
    __syncthreads();

    // phase 2: reserve this block's run inside each bucket region
    for (int t = tid; t < NBk; t += 512) {
        int c = hist[t];
        runbase[t] = (c > 0) ? atomicAdd(&gcnt[t], c) : 0;
    }
    __syncthreads();

    // phase 3: scatter packed edges
    for (int k = 0; k < 32; ++k) {
        long long e = base + (long long)k * 512 + tid;
        if (e < E) {
            int s = is64 ? (int)p64[e] : p32[e];
            int d = is64 ? (int)p64[E + e] : p32[E + e];
            int b = d >> BSH;
            int pos = atomicAdd(&lcur[b], 1);
            payload[(size_t)b * CAP + runbase[b] + pos] =
                ((unsigned)s << BSH) | (unsigned)(d & (BNODES - 1));
        }
    }
}

__global__ void dinv_kernel(const unsigned* __restrict__ deg,
                            float* __restrict__ dinv, int N) {
    int i = blockIdx.x * 256 + threadIdx.x;
    if (i < N) dinv[i] = rsqrtf((float)deg[i] + 1.0f);  // +1 = self-loop
}

// ---------------------------------------------------------------------------
// GEMM1: hs[i][c] = (x[i] @ W1[:,c]) * dinv[i], padded to 16 ch (ch15 = 0).
// ---------------------------------------------------------------------------
__global__ __launch_bounds__(256) void gemm1_kernel(
    const float* __restrict__ x, const float* __restrict__ W1,
    const float* __restrict__ dinv, float* __restrict__ hs, int N) {
    __shared__ float Wl[N_IN * N_HIDP];
    for (int i = threadIdx.x; i < N_IN * N_HIDP; i += 256) {
        int k = i >> 4, c = i & 15;
        Wl[i] = (c < N_HID) ? W1[k * N_HID + c] : 0.f;
    }
    __syncthreads();
    const float4* __restrict__ Wl4 = (const float4*)Wl;
    const float4* __restrict__ x4  = (const float4*)x;

    int r0 = blockIdx.x * 512 + threadIdx.x;
    int r1 = r0 + 256;
    int r0c = r0 < N ? r0 : N - 1;
    int r1c = r1 < N ? r1 : N - 1;

    float acc0[16], acc1[16];
#pragma unroll
    for (int c = 0; c < 16; ++c) { acc0[c] = 0.f; acc1[c] = 0.f; }

    for (int k4 = 0; k4 < 32; ++k4) {
        float4 xv0 = x4[r0c * 32 + k4];
        float4 xv1 = x4[r1c * 32 + k4];
        float xs0[4] = {xv0.x, xv0.y, xv0.z, xv0.w};
        float xs1[4] = {xv1.x, xv1.y, xv1.z, xv1.w};
#pragma unroll
        for (int t = 0; t < 4; ++t) {
            int k = k4 * 4 + t;
            float4 wa = Wl4[k * 4 + 0];
            float4 wb = Wl4[k * 4 + 1];
            float4 wc = Wl4[k * 4 + 2];
            float4 wd = Wl4[k * 4 + 3];
            float wf[16] = {wa.x, wa.y, wa.z, wa.w, wb.x, wb.y, wb.z, wb.w,
                            wc.x, wc.y, wc.z, wc.w, wd.x, wd.y, wd.z, wd.w};
#pragma unroll
            for (int c = 0; c < 16; ++c) {
                acc0[c] = fmaf(xs0[t], wf[c], acc0[c]);
                acc1[c] = fmaf(xs1[t], wf[c], acc1[c]);
            }
        }
    }
    float4* __restrict__ hs4 = (float4*)hs;
    if (r0 < N) {
        float di = dinv[r0];
#pragma unroll
        for (int j = 0; j < 4; ++j)
            hs4[r0 * 4 + j] = make_float4(acc0[4*j]*di, acc0[4*j+1]*di,
                                          acc0[4*j+2]*di, acc0[4*j+3]*di);
    }
    if (r1 < N) {
        float di = dinv[r1];
#pragma unroll
        for (int j = 0; j < 4; ++j)
            hs4[r1 * 4 + j] = make_float4(acc1[4*j]*di, acc1[4*j+1]*di,
                                          acc1[4*j+2]*di, acc1[4*j+3]*di);
    }
}

// ---------------------------------------------------------------------------
// Agg: one block per (bucket, slice). Accumulate messages into a 256x16 LDS
// table (stride 17) with ds_add_f32, then dump partials coalesced.
// 17 KB LDS -> 8 blocks/CU; grid = NB*4 = 3128; 4 gathers in flight/thread.
// ---------------------------------------------------------------------------
__global__ __launch_bounds__(256) void agg_kernel(
    const unsigned* __restrict__ payload, const int* __restrict__ gcnt,
    const float* __restrict__ feat, float* __restrict__ part) {
    __shared__ float acc[BNODES * 17];
    const int tid = threadIdx.x;
    const int bucket = blockIdx.x >> 2;
    const int slice  = blockIdx.x & 3;

    for (int k = tid; k < BNODES * 17; k += 256) acc[k] = 0.f;
    __syncthreads();

    int cnt = gcnt[bucket];
    if (cnt > CAP) cnt = CAP;
    int q  = (cnt + 3) >> 2;
    int s0 = slice * q;
    int s1 = min(cnt, s0 + q);

    const unsigned* __restrict__ pay = payload + (size_t)bucket * CAP;
    const int c  = tid & 15;
    const int el = tid >> 4;  // 0..15

    int j = s0 + el;
    for (; j + 48 < s1; j += 64) {
        unsigned p0 = pay[j];
        unsigned p1 = pay[j + 16];
        unsigned p2 = pay[j + 32];
        unsigned p3 = pay[j + 48];
        float v0 = feat[(p0 >> BSH) * N_HIDP + c];
        float v1 = feat[(p1 >> BSH) * N_HIDP + c];
        float v2 = feat[(p2 >> BSH) * N_HIDP + c];
        float v3 = feat[(p3 >> BSH) * N_HIDP + c];
        atomicAdd(&acc[(p0 & (BNODES - 1)) * 17 + c], v0);
        atomicAdd(&acc[(p1 & (BNODES - 1)) * 17 + c], v1);
        atomicAdd(&acc[(p2 & (BNODES - 1)) * 17 + c], v2);
        atomicAdd(&acc[(p3 & (BNODES - 1)) * 17 + c], v3);
    }
    for (; j < s1; j += 16) {
        unsigned pk = pay[j];
        float v = feat[(pk >> BSH) * N_HIDP + c];
        atomicAdd(&acc[(pk & (BNODES - 1)) * 17 + c], v);
    }
    __syncthreads();

    float* __restrict__ outp = part + (size_t)blockIdx.x * (BNODES * N_HIDP);
    for (int k = tid; k < BNODES * N_HIDP; k += 256)
        outp[k] = acc[(k >> 4) * 17 + (k & 15)];
}

// finalize1: hs2[i][c] = relu(dinv*(sum of 4 partials + hs_self) + b1) * dinv
__global__ void finalize1_kernel(const float* __restrict__ part,
                                 const float* __restrict__ hs,
                                 const float* __restrict__ dinv,
                                 const float* __restrict__ b1,
                                 float* __restrict__ hs2, int N) {
    int t = blockIdx.x * 256 + threadIdx.x;
    int i = t >> 4, c = t & 15;
    if (i >= N) return;
    int bucket = i >> BSH, n = i & (BNODES - 1);
    size_t o = ((size_t)(bucket * SLICES)) * (BNODES * N_HIDP) + n * N_HIDP + c;
    const size_t st = BNODES * N_HIDP;
    float di = dinv[i];
    float sum = ((part[o] + part[o + st]) + (part[o + 2 * st] + part[o + 3 * st]))
                + hs[(size_t)i * N_HIDP + c];
    float b = (c < N_HID) ? b1[c] : 0.f;
    float v = fmaxf(di * sum + b, 0.f);
    hs2[(size_t)i * N_HIDP + c] = v * di;
}

// finalize2: out[i] = (dinv*(sum of 4 partials + hs2_self)) @ W2 + b2
__global__ __launch_bounds__(256) void finalize2_kernel(
    const float* __restrict__ part, const float* __restrict__ hs2,
    const float* __restrict__ dinv, const float* __restrict__ W2,
    const float* __restrict__ b2, float* __restrict__ out, int N) {
    __shared__ float W2l[N_HIDP * N_OUT];
    __shared__ float ubuf[16][17];
    for (int t = threadIdx.x; t < N_HIDP * N_OUT; t += 256)
        W2l[t] = (t < N_HID * N_OUT) ? W2[t] : 0.f;

    int c = threadIdx.x & 15, qn = threadIdx.x >> 4;
    int i = blockIdx.x * 16 + qn;
    int iw = i < N ? i : N - 1;
    int bucket = iw >> BSH, n = iw & (BNODES - 1);
    size_t o = ((size_t)(bucket * SLICES)) * (BNODES * N_HIDP) + n * N_HIDP + c;
    const size_t st = BNODES * N_HIDP;
    float di = dinv[iw];
    float sum = ((part[o] + part[o + st]) + (part[o + 2 * st] + part[o + 3 * st]))
                + hs2[(size_t)iw * N_HIDP + c];
    ubuf[qn][c] = di * sum;
    __syncthreads();

    float a0 = b2[c], a1 = b2[c + 16];
#pragma unroll
    for (int k = 0; k < N_HID; ++k) {
        float uv = ubuf[qn][k];
        a0 = fmaf(uv, W2l[k * N_OUT + c], a0);
        a1 = fmaf(uv, W2l[k * N_OUT + c + 16], a1);
    }
    if (i < N) {
        out[(size_t)i * N_OUT + c] = a0;
        out[(size_t)i * N_OUT + c + 16] = a1;
    }
}

// ---------------------------------------------------------------------------
extern "C" void kernel_launch(void* const* d_in, const int* in_sizes, int n_in,
                              void* d_out, int out_size, void* d_ws, size_t ws_size,
                              hipStream_t stream) {
    const float* x   = (const float*)d_in[0];
    const void*  eix = d_in[1];
    const float* W1  = (const float*)d_in[2];
    const float* b1  = (const float*)d_in[3];
    const float* W2  = (const float*)d_in[4];
    const float* b2  = (const float*)d_in[5];
    float* out = (float*)d_out;

    const int N = in_sizes[0] / N_IN;   // 200000
    const int E = in_sizes[1] / 2;      // 6400000
    const int NB = (N + BNODES - 1) >> BSH;  // 782

    char* ws = (char*)d_ws;
    size_t off = 0;
    auto alloc = [&](size_t bytes) -> void* {
        void* p = ws + off;
        off += (bytes + 255) & ~(size_t)255;
        return p;
    };
    unsigned* payload = (unsigned*)alloc((size_t)NB * CAP * 4);              // 32 MB
    float*    part    = (float*)alloc((size_t)NB * SLICES * BNODES * N_HIDP * 4); // 51 MB
    unsigned* deg     = (unsigned*)alloc((size_t)N * 4);
    float*    dinv    = (float*)alloc((size_t)N * 4);
    float*    hs      = (float*)alloc((size_t)N * N_HIDP * 4);
    float*    hs2     = (float*)alloc((size_t)N * N_HIDP * 4);
    int*      gcnt    = (int*)alloc((size_t)NB * 4);
    int*      flag    = (int*)alloc(256);

    hipMemsetAsync(deg, 0, (size_t)N * 4, stream);
    hipMemsetAsync(gcnt, 0, (size_t)NB * 4, stream);

    detect_kernel<<<1, 256, 0, stream>>>((const int*)eix, flag);

    const int npart = (E + 16383) / 16384;  // 391
    partition_kernel<<<npart, 512, 0, stream>>>(eix, E, NB, flag, deg, gcnt, payload);

    dinv_kernel<<<(N + 255) / 256, 256, 0, stream>>>(deg, dinv, N);
    gemm1_kernel<<<(N + 511) / 512, 256, 0, stream>>>(x, W1, dinv, hs, N);

    const int nagg = NB * SLICES;  // 3128
    agg_kernel<<<nagg, 256, 0, stream>>>(payload, gcnt, hs, part);
    finalize1_kernel<<<(N * 16 + 255) / 256, 256, 0, stream>>>(part, hs, dinv, b1, hs2, N);

    agg_kernel<<<nagg, 256, 0, stream>>>(payload, gcnt, hs2, part);
    finalize2_kernel<<<(N + 15) / 16, 256, 0, stream>>>(part, hs2, dinv, W2, b2, out, N);
}

// Round 5
// 1109.175 us; speedup vs baseline: 1.6951x; 1.5062x over previous
//
#include <hip/hip_runtime.h>

#define N_IN   128
#define N_HID  15
#define N_HIDP 16
#define N_OUT  32

// ---------------------------------------------------------------------------
// Detect int64 vs int32 edge payload: if int64, every odd 32-bit word (high
// word of a value < 2^31) is 0.
// ---------------------------------------------------------------------------
__global__ void detect_kernel(const int* __restrict__ idx, int* __restrict__ flag) {
    __shared__ int nz;
    if (threadIdx.x == 0) nz = 0;
    __syncthreads();
    if (idx[2 * threadIdx.x + 1] != 0) atomicOr(&nz, 1);
    __syncthreads();
    if (threadIdx.x == 0) *flag = (nz == 0) ? 1 : 0;
}

// In-degree (excluding self-loops), reading dst straight from edge_index.
__global__ void deg_kernel(const void* __restrict__ idx, int E,
                           const int* __restrict__ flag,
                           unsigned* __restrict__ deg) {
    int e = blockIdx.x * 256 + threadIdx.x;
    if (e >= E) return;
    int d = (*flag) ? (int)((const long long*)idx)[E + e]
                    : ((const int*)idx)[E + e];
    atomicAdd(&deg[d], 1u);
}

__global__ void dinv_kernel(const unsigned* __restrict__ deg,
                            float* __restrict__ dinv, int N) {
    int i = blockIdx.x * 256 + threadIdx.x;
    if (i < N) dinv[i] = rsqrtf((float)deg[i] + 1.0f);  // +1 = self-loop
}

// ---------------------------------------------------------------------------
// GEMM1: hs[i][c] = (x[i] @ W1[:,c]) * dinv[i], padded to 16 ch (ch15 = 0).
// ---------------------------------------------------------------------------
__global__ __launch_bounds__(256) void gemm1_kernel(
    const float* __restrict__ x, const float* __restrict__ W1,
    const float* __restrict__ dinv, float* __restrict__ hs, int N) {
    __shared__ float Wl[N_IN * N_HIDP];
    for (int i = threadIdx.x; i < N_IN * N_HIDP; i += 256) {
        int k = i >> 4, c = i & 15;
        Wl[i] = (c < N_HID) ? W1[k * N_HID + c] : 0.f;
    }
    __syncthreads();
    const float4* __restrict__ Wl4 = (const float4*)Wl;
    const float4* __restrict__ x4  = (const float4*)x;

    int r0 = blockIdx.x * 512 + threadIdx.x;
    int r1 = r0 + 256;
    int r0c = r0 < N ? r0 : N - 1;
    int r1c = r1 < N ? r1 : N - 1;

    float acc0[16], acc1[16];
#pragma unroll
    for (int c = 0; c < 16; ++c) { acc0[c] = 0.f; acc1[c] = 0.f; }

    for (int k4 = 0; k4 < 32; ++k4) {
        float4 xv0 = x4[r0c * 32 + k4];
        float4 xv1 = x4[r1c * 32 + k4];
        float xs0[4] = {xv0.x, xv0.y, xv0.z, xv0.w};
        float xs1[4] = {xv1.x, xv1.y, xv1.z, xv1.w};
#pragma unroll
        for (int t = 0; t < 4; ++t) {
            int k = k4 * 4 + t;
            float4 wa = Wl4[k * 4 + 0];
            float4 wb = Wl4[k * 4 + 1];
            float4 wc = Wl4[k * 4 + 2];
            float4 wd = Wl4[k * 4 + 3];
            float wf[16] = {wa.x, wa.y, wa.z, wa.w, wb.x, wb.y, wb.z, wb.w,
                            wc.x, wc.y, wc.z, wc.w, wd.x, wd.y, wd.z, wd.w};
#pragma unroll
            for (int c = 0; c < 16; ++c) {
                acc0[c] = fmaf(xs0[t], wf[c], acc0[c]);
                acc1[c] = fmaf(xs1[t], wf[c], acc1[c]);
            }
        }
    }
    float4* __restrict__ hs4 = (float4*)hs;
    if (r0 < N) {
        float di = dinv[r0];
#pragma unroll
        for (int j = 0; j < 4; ++j)
            hs4[r0 * 4 + j] = make_float4(acc0[4*j]*di, acc0[4*j+1]*di,
                                          acc0[4*j+2]*di, acc0[4*j+3]*di);
    }
    if (r1 < N) {
        float di = dinv[r1];
#pragma unroll
        for (int j = 0; j < 4; ++j)
            hs4[r1 * 4 + j] = make_float4(acc1[4*j]*di, acc1[4*j+1]*di,
                                          acc1[4*j+2]*di, acc1[4*j+3]*di);
    }
}

// ---------------------------------------------------------------------------
// Scatter: 16 lanes per edge (c = lane&15), 4 edges per thread. All 4 gathers
// issued before the 4 fire-and-forget atomics so 4 random lines stay in
// flight per lane. Edge ids laid out k*NG+G so the src/dst index loads are
// fully coalesced across groups for each k. Zero messages skipped (layer 2:
// ~50% post-ReLU zeros; layer 1: skips the c==15 pad lane).
// ---------------------------------------------------------------------------
__global__ __launch_bounds__(256) void scatter_kernel(
    const void* __restrict__ idx, int E, const int* __restrict__ flag,
    const float* __restrict__ feat, float* __restrict__ agg) {
    const int c = threadIdx.x & 15;
    const long long G  = (long long)blockIdx.x * 16 + (threadIdx.x >> 4);
    const long long NG = (long long)gridDim.x * 16;
    const bool is64 = (*flag != 0);
    const long long* p64 = (const long long*)idx;
    const int*       p32 = (const int*)idx;

    int s[4], d[4];
    bool ok[4];
#pragma unroll
    for (int k = 0; k < 4; ++k) {
        long long e = (long long)k * NG + G;
        ok[k] = (e < E);
        long long ec = ok[k] ? e : 0;
        if (is64) { s[k] = (int)p64[ec]; d[k] = (int)p64[E + ec]; }
        else      { s[k] = p32[ec];      d[k] = p32[E + ec]; }
    }
    float v[4];
#pragma unroll
    for (int k = 0; k < 4; ++k)
        v[k] = feat[(size_t)s[k] * N_HIDP + c];
#pragma unroll
    for (int k = 0; k < 4; ++k)
        if (ok[k] && v[k] != 0.f)
            atomicAdd(&agg[(size_t)d[k] * N_HIDP + c], v[k]);
}

// finalize1: hs2[i][c] = relu(dinv*(agg+hs_self) + b1) * dinv  (pad ch -> 0)
__global__ void finalize1_kernel(const float* __restrict__ agg,
                                 const float* __restrict__ hs,
                                 const float* __restrict__ dinv,
                                 const float* __restrict__ b1,
                                 float* __restrict__ hs2, int N) {
    int t = blockIdx.x * 256 + threadIdx.x;
    int i = t >> 4, c = t & 15;
    if (i >= N) return;
    float di = dinv[i];
    float sum = agg[(size_t)i * N_HIDP + c] + hs[(size_t)i * N_HIDP + c];
    float b = (c < N_HID) ? b1[c] : 0.f;
    float v = fmaxf(di * sum + b, 0.f);
    hs2[(size_t)i * N_HIDP + c] = v * di;
}

// finalize2: out[i] = (dinv*(agg+hs2_self)) @ W2 + b2, LDS-staged u.
__global__ __launch_bounds__(256) void finalize2_kernel(
    const float* __restrict__ agg, const float* __restrict__ hs2,
    const float* __restrict__ dinv, const float* __restrict__ W2,
    const float* __restrict__ b2, float* __restrict__ out, int N) {
    __shared__ float W2l[N_HIDP * N_OUT];
    __shared__ float ubuf[16][17];
    for (int t = threadIdx.x; t < N_HIDP * N_OUT; t += 256)
        W2l[t] = (t < N_HID * N_OUT) ? W2[t] : 0.f;

    int c = threadIdx.x & 15, q = threadIdx.x >> 4;
    int i = blockIdx.x * 16 + q;
    int iw = i < N ? i : N - 1;
    float di = dinv[iw];
    ubuf[q][c] = di * (agg[(size_t)iw * N_HIDP + c] + hs2[(size_t)iw * N_HIDP + c]);
    __syncthreads();

    float a0 = b2[c], a1 = b2[c + 16];
#pragma unroll
    for (int k = 0; k < N_HID; ++k) {
        float uv = ubuf[q][k];
        a0 = fmaf(uv, W2l[k * N_OUT + c], a0);
        a1 = fmaf(uv, W2l[k * N_OUT + c + 16], a1);
    }
    if (i < N) {
        out[(size_t)i * N_OUT + c] = a0;
        out[(size_t)i * N_OUT + c + 16] = a1;
    }
}

// ---------------------------------------------------------------------------
extern "C" void kernel_launch(void* const* d_in, const int* in_sizes, int n_in,
                              void* d_out, int out_size, void* d_ws, size_t ws_size,
                              hipStream_t stream) {
    const float* x   = (const float*)d_in[0];
    const void*  eix = d_in[1];
    const float* W1  = (const float*)d_in[2];
    const float* b1  = (const float*)d_in[3];
    const float* W2  = (const float*)d_in[4];
    const float* b2  = (const float*)d_in[5];
    float* out = (float*)d_out;

    const int N = in_sizes[0] / N_IN;   // 200000
    const int E = in_sizes[1] / 2;      // 6400000

    char* ws = (char*)d_ws;
    size_t off = 0;
    auto alloc = [&](size_t bytes) -> void* {
        void* p = ws + off;
        off += (bytes + 255) & ~(size_t)255;
        return p;
    };
    unsigned* deg  = (unsigned*)alloc((size_t)N * 4);
    float*    dinv = (float*)alloc((size_t)N * 4);
    float*    hs   = (float*)alloc((size_t)N * N_HIDP * 4);
    float*    hs2  = (float*)alloc((size_t)N * N_HIDP * 4);
    float*    agg  = (float*)alloc((size_t)N * N_HIDP * 4);
    int*      flag = (int*)alloc(256);

    hipMemsetAsync(deg, 0, (size_t)N * 4, stream);
    hipMemsetAsync(agg, 0, (size_t)N * N_HIDP * 4, stream);

    detect_kernel<<<1, 256, 0, stream>>>((const int*)eix, flag);
    deg_kernel<<<(E + 255) / 256, 256, 0, stream>>>(eix, E, flag, deg);
    dinv_kernel<<<(N + 255) / 256, 256, 0, stream>>>(deg, dinv, N);
    gemm1_kernel<<<(N + 511) / 512, 256, 0, stream>>>(x, W1, dinv, hs, N);

    const int sblocks = (E + 63) / 64;   // 4 edges/thread, 16 lanes/edge
    scatter_kernel<<<sblocks, 256, 0, stream>>>(eix, E, flag, hs, agg);
    finalize1_kernel<<<(N * 16 + 255) / 256, 256, 0, stream>>>(agg, hs, dinv, b1, hs2, N);

    hipMemsetAsync(agg, 0, (size_t)N * N_HIDP * 4, stream);
    scatter_kernel<<<sblocks, 256, 0, stream>>>(eix, E, flag, hs2, agg);
    finalize2_kernel<<<(N + 15) / 16, 256, 0, stream>>>(agg, hs2, dinv, W2, b2, out, N);
}